// Round 18
// baseline (912.131 us; speedup 1.0000x reference)
//
#include <hip/hip_runtime.h>

typedef __attribute__((ext_vector_type(4))) float f32x4;
typedef __attribute__((ext_vector_type(4))) int   i32x4;
typedef __attribute__((ext_vector_type(8))) short s16x8;

#define MFMA16(a, b, c)  __builtin_amdgcn_mfma_f32_16x16x32_bf16((a), (b), (c), 0, 0, 0)
#define MFMAI8(a, b, c)  __builtin_amdgcn_mfma_i32_16x16x64_i8((a), (b), (c), 0, 0, 0)

#define QINV (1.0f / 252.0f)

typedef __attribute__((address_space(3))) unsigned int lds_uint;
typedef const __attribute__((address_space(1))) unsigned int glob_uint;
__device__ __forceinline__ void glds16(const void* g, void* l) {
    __builtin_amdgcn_global_load_lds((glob_uint*)g, (lds_uint*)l, 16, 0, 0);
}

#define SBARL()                                                                \
    {                                                                          \
        __builtin_amdgcn_sched_barrier(0);                                     \
        asm volatile("s_waitcnt lgkmcnt(0)" ::: "memory");                     \
        __builtin_amdgcn_s_barrier();                                          \
        __builtin_amdgcn_sched_barrier(0);                                     \
    }
#define SBAR()                                                                 \
    {                                                                          \
        __builtin_amdgcn_sched_barrier(0);                                     \
        __builtin_amdgcn_s_barrier();                                          \
        __builtin_amdgcn_sched_barrier(0);                                     \
    }

// ---------- bf16 helpers (RNE) ----------
__device__ inline unsigned short f2bf(float f) {
    unsigned int u = __float_as_uint(f);
    return (unsigned short)((u + 0x7FFFu + ((u >> 16) & 1u)) >> 16);
}
__device__ inline float bf2f(unsigned short b) {
    return __uint_as_float(((unsigned int)b) << 16);
}

// ---------- pack W [K][1024] f32 -> THREE bf16 levels (W_in path) ----------
__global__ __launch_bounds__(256) void k_pack3(const float* __restrict__ W,
                                               unsigned short* __restrict__ L1,
                                               unsigned short* __restrict__ L2,
                                               unsigned short* __restrict__ L3,
                                               int K) {
    int idx = blockIdx.x * 256 + threadIdx.x;
    if (idx >= K * 1024) return;
    int k = idx >> 10;
    int n = idx & 1023;
    float x = W[idx];
    unsigned short h1 = f2bf(x);  float r1 = x - bf2f(h1);
    unsigned short h2 = f2bf(r1); float r2 = r1 - bf2f(h2);
    unsigned short h3 = f2bf(r2);
    size_t o = ((size_t)(k >> 5) << 15) + ((size_t)n << 5) + (k & 31);
    L1[o] = h1; L2[o] = h2; L3[o] = h3;
}

// ---------- per-column max|W_rec| -> t1[n] = max/126 ----------
__global__ __launch_bounds__(256) void k_colmax(const float* __restrict__ W,
                                                float* __restrict__ t1) {
    __shared__ float red[256];
    int n = blockIdx.x;
    float m = 0.f;
    for (int k = threadIdx.x; k < 1024; k += 256)
        m = fmaxf(m, fabsf(W[(size_t)k * 1024 + n]));
    red[threadIdx.x] = m;
    __syncthreads();
    for (int s = 128; s > 0; s >>= 1) {
        if (threadIdx.x < s) red[threadIdx.x] = fmaxf(red[threadIdx.x], red[threadIdx.x + s]);
        __syncthreads();
    }
    if (threadIdx.x == 0) t1[n] = fmaxf(red[0], 1e-30f) * (1.0f / 126.0f);
}

// ---------- pack W_rec -> 3 i8 digits as MFMA-ready 1KB frags ----------
__global__ __launch_bounds__(256) void k_packq(const float* __restrict__ W,
                                               const float* __restrict__ t1a,
                                               signed char* __restrict__ Q) {
    int idx = blockIdx.x * 256 + threadIdx.x;   // k*1024 + n
    int k = idx >> 10;
    int n = idx & 1023;
    float x = W[idx];
    float T1 = t1a[n];
    float T2 = T1 * QINV;
    float T3 = T2 * QINV;
    float q1 = rintf(x / T1);  float r1 = fmaf(-q1, T1, x);
    float q2 = rintf(r1 / T2); float r2 = fmaf(-q2, T2, r1);
    float q3 = rintf(r2 / T3);
    int kt = k >> 6, cg = n >> 4;
    int lane = (((k >> 4) & 3) << 4) | (n & 15);
    size_t base = ((size_t)((kt * 64 + cg) * 3)) << 10;
    size_t lj = (size_t)lane * 16 + (k & 15);
    Q[base + lj]        = (signed char)(int)q1;
    Q[base + 1024 + lj] = (signed char)(int)q2;
    Q[base + 2048 + lj] = (signed char)(int)q3;
}

// ---------- main: cooperative 256 blocks x 512 thr; octet (8o..8o+7) = rows
// 64o..+64; member h owns cols h*128..+128 (0.375 MB slab; h == XCD).
// 8-way pairwise L3 bit exchange, hidden under own-kt MFMAs. ----------
#define FSTR 33
#define LDS_SPK    0        // i8 [64][1024] XOR-swizzled, SINGLE buffer (64KB)
#define LDS_DEC    65536
#define LDS_FRQ    66560
#define LDS_T1     67584
#define LDS_RING   68608    // 8 waves x 9216 (3 kt-slots x 3KB) -> 142336
#define LDS_PLDS   68608    // f32 [64][136] (phase D; ring dead)
#define LDS_TOTAL  142336

// consume slot SLOT (kt = KT), 12 MFMA (4 m-tiles x 3 lvl), reissue kt NKT.
#define RNT(SLOT, KT, NKT)                                                     \
    {                                                                          \
        asm volatile("s_waitcnt vmcnt(6)" ::: "memory");                       \
        __builtin_amdgcn_sched_barrier(0);                                     \
        const char* sl = ring + (SLOT) * 3072;                                 \
        i32x4 Bv0 = *(const i32x4*)(sl + lane16);                              \
        i32x4 Bv1 = *(const i32x4*)(sl + 1024 + lane16);                       \
        i32x4 Bv2 = *(const i32x4*)(sl + 2048 + lane16);                       \
        i32x4 Af0 = *(const i32x4*)(smem + (((llo)*1024 + (KT)*64 + lhi*16) ^ ax));       \
        i32x4 Af1 = *(const i32x4*)(smem + (((16 + llo)*1024 + (KT)*64 + lhi*16) ^ ax));  \
        i32x4 Af2 = *(const i32x4*)(smem + (((32 + llo)*1024 + (KT)*64 + lhi*16) ^ ax));  \
        i32x4 Af3 = *(const i32x4*)(smem + (((48 + llo)*1024 + (KT)*64 + lhi*16) ^ ax));  \
        acc[0][0] = MFMAI8(Af0, Bv0, acc[0][0]);                               \
        acc[1][0] = MFMAI8(Af1, Bv0, acc[1][0]);                               \
        acc[2][0] = MFMAI8(Af2, Bv0, acc[2][0]);                               \
        acc[3][0] = MFMAI8(Af3, Bv0, acc[3][0]);                               \
        acc[0][1] = MFMAI8(Af0, Bv1, acc[0][1]);                               \
        acc[1][1] = MFMAI8(Af1, Bv1, acc[1][1]);                               \
        acc[2][1] = MFMAI8(Af2, Bv1, acc[2][1]);                               \
        acc[3][1] = MFMAI8(Af3, Bv1, acc[3][1]);                               \
        acc[0][2] = MFMAI8(Af0, Bv2, acc[0][2]);                               \
        acc[1][2] = MFMAI8(Af1, Bv2, acc[1][2]);                               \
        acc[2][2] = MFMAI8(Af2, Bv2, acc[2][2]);                               \
        acc[3][2] = MFMAI8(Af3, Bv2, acc[3][2]);                               \
        __builtin_amdgcn_sched_barrier(0);                                     \
        const signed char* bq = WrQ + (((size_t)(((NKT)*64 + cg)*3)) << 10) + lane16; \
        glds16(bq,        (void*)sl);                                          \
        glds16(bq + 1024, (void*)(sl + 1024));                                 \
        glds16(bq + 2048, (void*)(sl + 2048));                                 \
    }
#define RNTL(SLOT, KT, N)                                                      \
    {                                                                          \
        asm volatile("s_waitcnt vmcnt(" #N ")" ::: "memory");                  \
        __builtin_amdgcn_sched_barrier(0);                                     \
        const char* sl = ring + (SLOT) * 3072;                                 \
        i32x4 Bv0 = *(const i32x4*)(sl + lane16);                              \
        i32x4 Bv1 = *(const i32x4*)(sl + 1024 + lane16);                       \
        i32x4 Bv2 = *(const i32x4*)(sl + 2048 + lane16);                       \
        i32x4 Af0 = *(const i32x4*)(smem + (((llo)*1024 + (KT)*64 + lhi*16) ^ ax));       \
        i32x4 Af1 = *(const i32x4*)(smem + (((16 + llo)*1024 + (KT)*64 + lhi*16) ^ ax));  \
        i32x4 Af2 = *(const i32x4*)(smem + (((32 + llo)*1024 + (KT)*64 + lhi*16) ^ ax));  \
        i32x4 Af3 = *(const i32x4*)(smem + (((48 + llo)*1024 + (KT)*64 + lhi*16) ^ ax));  \
        acc[0][0] = MFMAI8(Af0, Bv0, acc[0][0]);                               \
        acc[1][0] = MFMAI8(Af1, Bv0, acc[1][0]);                               \
        acc[2][0] = MFMAI8(Af2, Bv0, acc[2][0]);                               \
        acc[3][0] = MFMAI8(Af3, Bv0, acc[3][0]);                               \
        acc[0][1] = MFMAI8(Af0, Bv1, acc[0][1]);                               \
        acc[1][1] = MFMAI8(Af1, Bv1, acc[1][1]);                               \
        acc[2][1] = MFMAI8(Af2, Bv1, acc[2][1]);                               \
        acc[3][1] = MFMAI8(Af3, Bv1, acc[3][1]);                               \
        acc[0][2] = MFMAI8(Af0, Bv2, acc[0][2]);                               \
        acc[1][2] = MFMAI8(Af1, Bv2, acc[1][2]);                               \
        acc[2][2] = MFMAI8(Af2, Bv2, acc[2][2]);                               \
        acc[3][2] = MFMAI8(Af3, Bv2, acc[3][2]);                               \
    }

__global__ __launch_bounds__(512, 2) void k_main(const float* __restrict__ fused,
                                                 const unsigned short* __restrict__ Wi1,
                                                 const unsigned short* __restrict__ Wi2,
                                                 const unsigned short* __restrict__ Wi3,
                                                 const float* __restrict__ b_in,
                                                 const signed char* __restrict__ WrQ,
                                                 const float* __restrict__ t1a,
                                                 const float* __restrict__ b_rec,
                                                 const float* __restrict__ rdec,
                                                 const float* __restrict__ rfrq,
                                                 const float* __restrict__ W_out,
                                                 const float* __restrict__ b_out,
                                                 char* __restrict__ sx,
                                                 float* __restrict__ pdb,
                                                 unsigned int* __restrict__ flags,
                                                 float* __restrict__ out) {
    extern __shared__ __align__(16) char smem[];
    const int tid = threadIdx.x;
    const int w = tid >> 6, lane = tid & 63;
    const int llo = lane & 15, lhi = lane >> 4;
    const int bid = blockIdx.x;
    const int q = bid >> 3, h = bid & 7;
    const int r0 = q * 64;
    const int cbase = h * 128;
    const int cg = h * 8 + w;            // this wave's global col-group
    const int lane16 = lane * 16;
    const int ax = (llo & 7) << 4;
    const int myc = cbase + w * 16 + llo;  // this thread's column

    // ---- phases A+B: base = fused @ W_in + b_in, per-kt staged (8KB dbuf) ----
    f32x4 bacc[4] = {};   // [m]
    {
        float* fb0 = (float*)smem;
        float* fb1 = (float*)(smem + 8448);
        for (int i = tid; i < 2048; i += 512) {
            int rr = i >> 5, cc = i & 31;
            fb0[rr * FSTR + cc] = fused[(size_t)(r0 + rr) * 768 + cc];
        }
        __syncthreads();
        for (int kt = 0; kt < 24; ++kt) {
            float* cur = (kt & 1) ? fb1 : fb0;
            float* nxt = (kt & 1) ? fb0 : fb1;
            if (kt < 23)
                for (int i = tid; i < 2048; i += 512) {
                    int rr = i >> 5, cc = i & 31;
                    nxt[rr * FSTR + cc] = fused[(size_t)(r0 + rr) * 768 + (kt + 1) * 32 + cc];
                }
            size_t boff = ((size_t)(kt * 1024 + myc) << 5) + lhi * 8;
            s16x8 b1 = *(const s16x8*)&Wi1[boff];
            s16x8 b2 = *(const s16x8*)&Wi2[boff];
            s16x8 b3 = *(const s16x8*)&Wi3[boff];
#pragma unroll
            for (int m = 0; m < 4; ++m) {
                const float* ap = cur + (m * 16 + llo) * FSTR + lhi * 8;
                s16x8 a1v, a2v, a3v;
#pragma unroll
                for (int j = 0; j < 8; ++j) {
                    float x = ap[j];
                    unsigned short h1 = f2bf(x);  float r1 = x - bf2f(h1);
                    unsigned short h2 = f2bf(r1); float r2 = r1 - bf2f(h2);
                    a1v[j] = (short)h1; a2v[j] = (short)h2; a3v[j] = (short)f2bf(r2);
                }
                bacc[m] = MFMA16(a1v, b1, bacc[m]);
                bacc[m] = MFMA16(a1v, b2, bacc[m]);
                bacc[m] = MFMA16(a2v, b1, bacc[m]);
                bacc[m] = MFMA16(a2v, b2, bacc[m]);
                bacc[m] = MFMA16(a1v, b3, bacc[m]);
                bacc[m] = MFMA16(a3v, b1, bacc[m]);
            }
            __syncthreads();
        }
    }

    // ---- params (own 128 cols) ----
    float* ldsDec = (float*)(smem + LDS_DEC);
    float* ldsFrq = (float*)(smem + LDS_FRQ);
    float* ldsT1  = (float*)(smem + LDS_T1);
    if (tid < 128) {
        int c = cbase + tid;
        ldsDec[tid] = (float)(0.55 + 0.4 / (1.0 + exp(-(double)rdec[c])));
        ldsFrq[tid] = (float)(0.10 + 0.9 / (1.0 + exp(-(double)rfrq[c])));
        ldsT1[tid]  = t1a[c];
    }

    // ---- t=0 inline; own spikes -> A-LDS; ballots -> L3; prologue ----
    float base2[4][4], mem[4][4], res[4][4];
    unsigned int pooled_pk[4] = {0, 0, 0, 0};
    char* ring = smem + LDS_RING + w * 9216;
    unsigned long long myb = 0;
    {
        float bb = b_in[myc];
        float brv = b_rec[myc];
#pragma unroll
        for (int m = 0; m < 4; ++m)
#pragma unroll
            for (int fr = 0; fr < 4; ++fr) {
                int row = m * 16 + lhi * 4 + fr;
                float b0 = __fadd_rn(bacc[m][fr], bb);
                base2[m][fr] = __fadd_rn(b0, brv);
                float m_ = __fadd_rn(0.f, b0);
                int s = (m_ > 1.0f) ? 1 : 0;
                res[m][fr] = 0.f;
                mem[m][fr] = __fadd_rn(m_, -(float)s);
                pooled_pk[m] += (unsigned int)s << (8 * fr);
                unsigned long long b = __ballot(s);
                myb = (lane == (m * 4 + fr)) ? b : myb;
                *(unsigned char*)(smem + ((row * 1024 + myc) ^ ((row & 7) << 4))) =
                    (unsigned char)s;
            }
    }
    if (lane < 16)
        __hip_atomic_store((unsigned long long*)(sx + q * 8192 + h * 1024 + w * 128 + lane * 8),
                           myb, __ATOMIC_RELAXED, __HIP_MEMORY_SCOPE_AGENT);
    __builtin_amdgcn_sched_barrier(0);
#pragma unroll
    for (int kk = 0; kk < 3; ++kk) {   // prologue: kt_seq[0..2]
        int kt = (2 * h + kk) & 15;
        const signed char* b = WrQ + (((size_t)((kt * 64 + cg) * 3)) << 10) + lane16;
        char* sl = ring + kk * 3072;
        glds16(b,        (void*)sl);
        glds16(b + 1024, (void*)(sl + 1024));
        glds16(b + 2048, (void*)(sl + 2048));
    }
    __builtin_amdgcn_sched_barrier(0);
    asm volatile("s_waitcnt vmcnt(9)" ::: "memory");   // bits (oldest) retired
    SBARL();
    if (tid == 0)
        __hip_atomic_store(&flags[q * 8 + h], 1u,
                           __ATOMIC_RELAXED, __HIP_MEMORY_SCOPE_AGENT);

    // ---- phase C: steps 1..31 ----
    for (int t = 1; t < 32; ++t) {
        i32x4 acc[4][3] = {};

        // own kts: i=0 (kt=2h, slot0), i=1 (kt=2h+1, slot1)
        RNT(0, 2 * h,     (2 * h + 3) & 15)
        RNT(1, 2 * h + 1, (2 * h + 4) & 15)

        // poll 7 partner flags in parallel
        if (tid < 8 && tid != h) {
            while (__hip_atomic_load(&flags[(t - 1) * 256 + q * 8 + tid],
                                     __ATOMIC_ACQUIRE, __HIP_MEMORY_SCOPE_AGENT) == 0)
                __builtin_amdgcn_s_sleep(2);
        }
        SBAR();
        // expand 7x128 partner ballots (448 threads x 2); wave 7 keeps its ring
        if (tid < 448) {
            int hh = tid >> 6;
            int hsrc = hh + (hh >= h ? 1 : 0);
            int inner = tid & 63;
#pragma unroll
            for (int e = 0; e < 2; ++e) {
                int idx = inner * 2 + e;
                unsigned long long B = __hip_atomic_load(
                    (unsigned long long*)(sx + (((t - 1) & 1) * 262144) + q * 8192
                                          + hsrc * 1024 + idx * 8),
                    __ATOMIC_RELAXED, __HIP_MEMORY_SCOPE_AGENT);
                int wsrc = idx >> 4, l = idx & 15;
                int m = l >> 2, fr = l & 3;
                int colb = hsrc * 128 + wsrc * 16;
#pragma unroll
                for (int l2 = 0; l2 < 4; ++l2) {
                    int row = m * 16 + l2 * 4 + fr;
                    unsigned int b16 = (unsigned int)(B >> (l2 * 16)) & 0xFFFFu;
                    i32x4 v;
#pragma unroll
                    for (int qq = 0; qq < 4; ++qq) {
                        unsigned int b4 = (b16 >> (qq * 4)) & 0xFu;
                        v[qq] = (int)((b4 & 1u) | ((b4 >> 1) & 1u) << 8 |
                                      ((b4 >> 2) & 1u) << 16 | ((b4 >> 3) & 1u) << 24);
                    }
                    *(i32x4*)(smem + ((row * 1024 + colb) ^ ((row & 7) << 4))) = v;
                }
            }
        }
        SBARL();

        // partner kts: i=2..12 steady, 13..15 drain
#pragma unroll
        for (int i = 2; i <= 12; ++i) {
            RNT(i % 3, (2 * h + i) & 15, (2 * h + i + 3) & 15)
        }
        RNTL(1, (2 * h + 13) & 15, 6)
        RNTL(2, (2 * h + 14) & 15, 3)
        RNTL(0, (2 * h + 15) & 15, 0)

        // state update (exact np op order)
        myb = 0;
        {
            int lc = w * 16 + llo;
            float dcc = ldsDec[lc], fqc = ldsFrq[lc], t1c = ldsT1[lc];
#pragma unroll
            for (int m = 0; m < 4; ++m)
#pragma unroll
                for (int fr = 0; fr < 4; ++fr) {
                    int row = m * 16 + lhi * 4 + fr;
                    float s3 = (float)acc[m][2][fr];
                    float s2 = fmaf(s3, QINV, (float)acc[m][1][fr]);
                    float rec = __fmul_rn(fmaf(s2, QINV, (float)acc[m][0][fr]), t1c);
                    float drive = __fadd_rn(base2[m][fr], rec);
                    float rnew = __fadd_rn(__fmul_rn(dcc, res[m][fr]),
                                           __fmul_rn(fqc, mem[m][fr]));
                    float tt = __fadd_rn(__fmul_rn(dcc, mem[m][fr]), drive);
                    float m_ = __fadd_rn(tt, -rnew);
                    int s = (m_ > 1.0f) ? 1 : 0;
                    res[m][fr] = rnew;
                    mem[m][fr] = __fadd_rn(m_, -(float)s);
                    pooled_pk[m] += (unsigned int)s << (8 * fr);
                    unsigned long long b = __ballot(s);
                    myb = (lane == (m * 4 + fr)) ? b : myb;
                    if (t < 31)
                        *(unsigned char*)(smem + ((row * 1024 + myc) ^ ((row & 7) << 4))) =
                            (unsigned char)s;
                }
        }
        if (t < 31) {
            if (lane < 16)
                __hip_atomic_store((unsigned long long*)(sx + ((t & 1) * 262144) + q * 8192
                                                         + h * 1024 + w * 128 + lane * 8),
                                   myb, __ATOMIC_RELAXED, __HIP_MEMORY_SCOPE_AGENT);
            __builtin_amdgcn_sched_barrier(0);
#pragma unroll
            for (int kk = 0; kk < 3; ++kk) {
                int kt = (2 * h + kk) & 15;
                const signed char* b = WrQ + (((size_t)((kt * 64 + cg) * 3)) << 10) + lane16;
                char* sl = ring + kk * 3072;
                glds16(b,        (void*)sl);
                glds16(b + 1024, (void*)(sl + 1024));
                glds16(b + 2048, (void*)(sl + 2048));
            }
            __builtin_amdgcn_sched_barrier(0);
            asm volatile("s_waitcnt vmcnt(9)" ::: "memory");
            SBARL();
            if (tid == 0)
                __hip_atomic_store(&flags[t * 256 + q * 8 + h], 1u,
                                   __ATOMIC_RELAXED, __HIP_MEMORY_SCOPE_AGENT);
        }
    }

    // ---- phase D: own-col f64 partials (2 per thread); h>0 ship f32; h==0 combine ----
    __syncthreads();
    float* plds = (float*)(smem + LDS_PLDS);
#pragma unroll
    for (int m = 0; m < 4; ++m) {
        int lc = w * 16 + llo;
#pragma unroll
        for (int fr = 0; fr < 4; ++fr)
            plds[(m * 16 + lhi * 4 + fr) * 136 + lc] =
                (float)((pooled_pk[m] >> (8 * fr)) & 255u) * 0.03125f;
    }
    __syncthreads();
    double part[2];
#pragma unroll
    for (int e = 0; e < 2; ++e) {
        int p = tid + e * 512;
        int row = p >> 4, o = p & 15;
        double s = 0.0;
        for (int j = 0; j < 128; ++j)
            s += (double)plds[row * 136 + j] * (double)W_out[(size_t)(cbase + j) * 16 + o];
        part[e] = s;
    }
    if (h != 0) {
#pragma unroll
        for (int e = 0; e < 2; ++e)
            __hip_atomic_store(&pdb[(q * 8 + h) * 1024 + tid + e * 512], (float)part[e],
                               __ATOMIC_RELAXED, __HIP_MEMORY_SCOPE_AGENT);
        __syncthreads();
        if (tid == 0)
            __hip_atomic_store(&flags[32 * 256 + q * 8 + h], 1u,
                               __ATOMIC_RELEASE, __HIP_MEMORY_SCOPE_AGENT);
    } else {
        if (tid < 8 && tid != 0) {
            while (__hip_atomic_load(&flags[32 * 256 + q * 8 + tid],
                                     __ATOMIC_ACQUIRE, __HIP_MEMORY_SCOPE_AGENT) == 0)
                __builtin_amdgcn_s_sleep(2);
        }
        __syncthreads();
#pragma unroll
        for (int e = 0; e < 2; ++e) {
            int p = tid + e * 512;
            int row = p >> 4, o = p & 15;
            double tot = part[e];
#pragma unroll
            for (int hp = 1; hp < 8; ++hp)
                tot += (double)__hip_atomic_load(&pdb[(q * 8 + hp) * 1024 + p],
                                                 __ATOMIC_RELAXED, __HIP_MEMORY_SCOPE_AGENT);
            out[(size_t)(r0 + row) * 16 + o] = __fadd_rn((float)tot, b_out[o]);
        }
    }
}

extern "C" void kernel_launch(void* const* d_in, const int* in_sizes, int n_in,
                              void* d_out, int out_size, void* d_ws, size_t ws_size,
                              hipStream_t stream) {
    const float* fused = (const float*)d_in[0];
    const float* W_in  = (const float*)d_in[1];
    const float* b_in  = (const float*)d_in[2];
    const float* W_rec = (const float*)d_in[3];
    const float* b_rec = (const float*)d_in[4];
    const float* W_out = (const float*)d_in[5];
    const float* b_out = (const float*)d_in[6];
    const float* rdec  = (const float*)d_in[7];
    const float* rfrq  = (const float*)d_in[8];

    // ws: WrQ 3MB | t1 | Wi 4.5MB | sx 512KB | pdb(f32) 1MB | flags 33KB (~9.3MB)
    char* ws = (char*)d_ws;
    signed char*    WrQ   = (signed char*)(ws);
    float*          t1a   = (float*)(ws + 3145728);
    unsigned short* Wi1   = (unsigned short*)(ws + 3407872);
    unsigned short* Wi2   = (unsigned short*)(ws + 4980736);
    unsigned short* Wi3   = (unsigned short*)(ws + 6553600);
    char*           sx    = ws + 8126464;
    float*          pdb   = (float*)(ws + 8650752);
    unsigned int*   flags = (unsigned int*)(ws + 9699328);
    float* out = (float*)d_out;

    hipFuncSetAttribute((const void*)k_main,
                        hipFuncAttributeMaxDynamicSharedMemorySize, LDS_TOTAL);

    hipMemsetAsync(flags, 0, 33 * 256 * 4, stream);
    hipLaunchKernelGGL(k_colmax, dim3(1024), dim3(256), 0, stream, W_rec, t1a);
    hipLaunchKernelGGL(k_packq, dim3(4096), dim3(256), 0, stream, W_rec, t1a, WrQ);
    hipLaunchKernelGGL(k_pack3, dim3(3072), dim3(256), 0, stream, W_in, Wi1, Wi2, Wi3, 768);

    void* args[] = {(void*)&fused, (void*)&Wi1, (void*)&Wi2, (void*)&Wi3, (void*)&b_in,
                    (void*)&WrQ, (void*)&t1a, (void*)&b_rec, (void*)&rdec, (void*)&rfrq,
                    (void*)&W_out, (void*)&b_out, (void*)&sx, (void*)&pdb, (void*)&flags,
                    (void*)&out};
    hipLaunchCooperativeKernel((void*)k_main, dim3(256), dim3(512), args, LDS_TOTAL, stream);
}

// Round 19
// 753.725 us; speedup vs baseline: 1.2102x; 1.2102x over previous
//
#include <hip/hip_runtime.h>

typedef __attribute__((ext_vector_type(4))) float f32x4;
typedef __attribute__((ext_vector_type(4))) int   i32x4;
typedef __attribute__((ext_vector_type(8))) short s16x8;

#define MFMA16(a, b, c)  __builtin_amdgcn_mfma_f32_16x16x32_bf16((a), (b), (c), 0, 0, 0)
#define MFMAI8(a, b, c)  __builtin_amdgcn_mfma_i32_16x16x64_i8((a), (b), (c), 0, 0, 0)

#define QINV (1.0f / 252.0f)

typedef __attribute__((address_space(3))) unsigned int lds_uint;
typedef const __attribute__((address_space(1))) unsigned int glob_uint;
__device__ __forceinline__ void glds16(const void* g, void* l) {
    __builtin_amdgcn_global_load_lds((glob_uint*)g, (lds_uint*)l, 16, 0, 0);
}

#define SBARL()                                                                \
    {                                                                          \
        __builtin_amdgcn_sched_barrier(0);                                     \
        asm volatile("s_waitcnt lgkmcnt(0)" ::: "memory");                     \
        __builtin_amdgcn_s_barrier();                                          \
        __builtin_amdgcn_sched_barrier(0);                                     \
    }

// ---------- bf16 helpers (RNE) ----------
__device__ inline unsigned short f2bf(float f) {
    unsigned int u = __float_as_uint(f);
    return (unsigned short)((u + 0x7FFFu + ((u >> 16) & 1u)) >> 16);
}
__device__ inline float bf2f(unsigned short b) {
    return __uint_as_float(((unsigned int)b) << 16);
}

// ---------- pack W [K][1024] f32 -> THREE bf16 levels (W_in path) ----------
__global__ __launch_bounds__(256) void k_pack3(const float* __restrict__ W,
                                               unsigned short* __restrict__ L1,
                                               unsigned short* __restrict__ L2,
                                               unsigned short* __restrict__ L3,
                                               int K) {
    int idx = blockIdx.x * 256 + threadIdx.x;
    if (idx >= K * 1024) return;
    int k = idx >> 10;
    int n = idx & 1023;
    float x = W[idx];
    unsigned short h1 = f2bf(x);  float r1 = x - bf2f(h1);
    unsigned short h2 = f2bf(r1); float r2 = r1 - bf2f(h2);
    unsigned short h3 = f2bf(r2);
    size_t o = ((size_t)(k >> 5) << 15) + ((size_t)n << 5) + (k & 31);
    L1[o] = h1; L2[o] = h2; L3[o] = h3;
}

// ---------- per-column max|W_rec| -> t1u bits (COALESCED + atomicMax) ----------
// 128 blocks x 8 rows each; positive-float bits are order-monotone.
__global__ __launch_bounds__(256) void k_colmax(const float* __restrict__ W,
                                                unsigned int* __restrict__ t1u) {
    __shared__ float cmax[1024];
    for (int i = threadIdx.x; i < 1024; i += 256) cmax[i] = 0.f;
    __syncthreads();
    int k0 = blockIdx.x * 8;
    for (int r = 0; r < 8; ++r)
        for (int c = threadIdx.x; c < 1024; c += 256)
            cmax[c] = fmaxf(cmax[c], fabsf(W[(size_t)(k0 + r) * 1024 + c]));
    __syncthreads();
    for (int c = threadIdx.x; c < 1024; c += 256)
        atomicMax(&t1u[c], __float_as_uint(cmax[c]));
}

// ---------- pack W_rec -> 3 i8 digits as MFMA-ready 1KB frags; also emit t1a ----------
__global__ __launch_bounds__(256) void k_packq(const float* __restrict__ W,
                                               const unsigned int* __restrict__ t1u,
                                               float* __restrict__ t1a,
                                               signed char* __restrict__ Q) {
    int idx = blockIdx.x * 256 + threadIdx.x;   // k*1024 + n
    int k = idx >> 10;
    int n = idx & 1023;
    float x = W[idx];
    float T1 = fmaxf(__uint_as_float(t1u[n]), 1e-30f) * (1.0f / 126.0f);
    if (k == 0) t1a[n] = T1;
    float T2 = T1 * QINV;
    float T3 = T2 * QINV;
    float q1 = rintf(x / T1);  float r1 = fmaf(-q1, T1, x);
    float q2 = rintf(r1 / T2); float r2 = fmaf(-q2, T2, r1);
    float q3 = rintf(r2 / T3);
    int kt = k >> 6, cg = n >> 4;
    int lane = (((k >> 4) & 3) << 4) | (n & 15);
    size_t base = ((size_t)((kt * 64 + cg) * 3)) << 10;
    size_t lj = (size_t)lane * 16 + (k & 15);
    Q[base + lj]        = (signed char)(int)q1;
    Q[base + 1024 + lj] = (signed char)(int)q2;
    Q[base + 2048 + lj] = (signed char)(int)q3;
}

// ---------- main: cooperative 256 blocks x 512 thr; quad rows 32q..+32,
// member h cols h*256..+256. Cyclic kt order hides the pairwise L3 spike
// exchange; per-thread polls + hoisted bits load (T14 split). ----------
#define FSTR 770
#define LDS_SPK    0        // i8 [32][1024] XOR-swizzled, SINGLE buffer
#define LDS_DEC    32768
#define LDS_FRQ    33792
#define LDS_T1     34816
#define LDS_RING   35840    // 8 waves x 12288 -> ends 134144
#define LDS_FUSED  35840    // f32 [32][770] (phases A/B only)
#define LDS_PLDS   35840    // f32 [32][264] (phase D)
#define LDS_TOTAL  134400

#define RING_NT(P, nt, BSRC)                                                   \
    {                                                                          \
        asm volatile("s_waitcnt vmcnt(9)" ::: "memory");                       \
        __builtin_amdgcn_sched_barrier(0);                                     \
        const char* sl = ring + (P) + (nt) * 3072;                             \
        i32x4 Bv0 = *(const i32x4*)(sl + lane16);                              \
        i32x4 Bv1 = *(const i32x4*)(sl + 1024 + lane16);                       \
        i32x4 Bv2 = *(const i32x4*)(sl + 2048 + lane16);                       \
        acc[0][nt][0] = MFMAI8(Af0, Bv0, acc[0][nt][0]);                       \
        acc[1][nt][0] = MFMAI8(Af1, Bv0, acc[1][nt][0]);                       \
        acc[0][nt][1] = MFMAI8(Af0, Bv1, acc[0][nt][1]);                       \
        acc[1][nt][1] = MFMAI8(Af1, Bv1, acc[1][nt][1]);                       \
        acc[0][nt][2] = MFMAI8(Af0, Bv2, acc[0][nt][2]);                       \
        acc[1][nt][2] = MFMAI8(Af1, Bv2, acc[1][nt][2]);                       \
        __builtin_amdgcn_sched_barrier(0);                                     \
        glds16((BSRC),        (void*)sl);                                      \
        glds16((BSRC) + 1024, (void*)(sl + 1024));                             \
        glds16((BSRC) + 2048, (void*)(sl + 2048));                             \
    }
#define RING_NTL(P, nt, N)                                                     \
    {                                                                          \
        asm volatile("s_waitcnt vmcnt(" #N ")" ::: "memory");                  \
        __builtin_amdgcn_sched_barrier(0);                                     \
        const char* sl = ring + (P) + (nt) * 3072;                             \
        i32x4 Bv0 = *(const i32x4*)(sl + lane16);                              \
        i32x4 Bv1 = *(const i32x4*)(sl + 1024 + lane16);                       \
        i32x4 Bv2 = *(const i32x4*)(sl + 2048 + lane16);                       \
        acc[0][nt][0] = MFMAI8(Af0, Bv0, acc[0][nt][0]);                       \
        acc[1][nt][0] = MFMAI8(Af1, Bv0, acc[1][nt][0]);                       \
        acc[0][nt][1] = MFMAI8(Af0, Bv1, acc[0][nt][1]);                       \
        acc[1][nt][1] = MFMAI8(Af1, Bv1, acc[1][nt][1]);                       \
        acc[0][nt][2] = MFMAI8(Af0, Bv2, acc[0][nt][2]);                       \
        acc[1][nt][2] = MFMAI8(Af1, Bv2, acc[1][nt][2]);                       \
    }

__global__ __launch_bounds__(512, 2) void k_main(const float* __restrict__ fused,
                                                 const unsigned short* __restrict__ Wi1,
                                                 const unsigned short* __restrict__ Wi2,
                                                 const unsigned short* __restrict__ Wi3,
                                                 const float* __restrict__ b_in,
                                                 const signed char* __restrict__ WrQ,
                                                 const float* __restrict__ t1a,
                                                 const float* __restrict__ b_rec,
                                                 const float* __restrict__ rdec,
                                                 const float* __restrict__ rfrq,
                                                 const float* __restrict__ W_out,
                                                 const float* __restrict__ b_out,
                                                 char* __restrict__ sx,
                                                 unsigned long long* __restrict__ pdb,
                                                 unsigned int* __restrict__ flags,
                                                 float* __restrict__ out) {
    extern __shared__ __align__(16) char smem[];
    const int tid = threadIdx.x;
    const int w = tid >> 6, lane = tid & 63;
    const int llo = lane & 15, lhi = lane >> 4;
    const int bid = blockIdx.x;
    const int q = bid >> 2, h = bid & 3;
    const int r0 = q * 32;
    const int cbase = h * 256;
    const int cg0 = h * 16 + w * 2;
    const int lane16 = lane * 16;
    const int ax = (llo & 7) << 4;

    // ---- phase A: stage fused[r0:r0+32][0:768] -> LDS ----
    float* fl = (float*)(smem + LDS_FUSED);
    for (int i = tid; i < 32 * 768; i += 512) {
        int rr = i / 768, cc = i - rr * 768;
        fl[rr * FSTR + cc] = fused[(size_t)(r0 + rr) * 768 + cc];
    }
    __syncthreads();

    // ---- phase B: base for 32 rows x own 256 cols (3x3-level bf16) ----
    f32x4 bacc[2][2] = {};   // [m][nt]
    for (int kt = 0; kt < 24; ++kt) {
        s16x8 a1v[2], a2v[2], a3v[2];
#pragma unroll
        for (int m = 0; m < 2; ++m) {
            const float* ap = fl + (m * 16 + llo) * FSTR + kt * 32 + lhi * 8;
#pragma unroll
            for (int j = 0; j < 8; ++j) {
                float x = ap[j];
                unsigned short h1 = f2bf(x);  float r1 = x - bf2f(h1);
                unsigned short h2 = f2bf(r1); float r2 = r1 - bf2f(h2);
                a1v[m][j] = (short)h1; a2v[m][j] = (short)h2; a3v[m][j] = (short)f2bf(r2);
            }
        }
#pragma unroll
        for (int nt = 0; nt < 2; ++nt) {
            int c = cbase + w * 32 + nt * 16 + llo;
            size_t boff = ((size_t)(kt * 1024 + c) << 5) + lhi * 8;
            s16x8 b1 = *(const s16x8*)&Wi1[boff];
            s16x8 b2 = *(const s16x8*)&Wi2[boff];
            s16x8 b3 = *(const s16x8*)&Wi3[boff];
#pragma unroll
            for (int m = 0; m < 2; ++m) {
                bacc[m][nt] = MFMA16(a1v[m], b1, bacc[m][nt]);
                bacc[m][nt] = MFMA16(a1v[m], b2, bacc[m][nt]);
                bacc[m][nt] = MFMA16(a2v[m], b1, bacc[m][nt]);
                bacc[m][nt] = MFMA16(a2v[m], b2, bacc[m][nt]);
                bacc[m][nt] = MFMA16(a1v[m], b3, bacc[m][nt]);
                bacc[m][nt] = MFMA16(a3v[m], b1, bacc[m][nt]);
            }
        }
    }
    __syncthreads();   // fused dead

    // ---- params (own 256 cols) ----
    float* ldsDec = (float*)(smem + LDS_DEC);
    float* ldsFrq = (float*)(smem + LDS_FRQ);
    float* ldsT1  = (float*)(smem + LDS_T1);
    if (tid < 256) {
        int c = cbase + tid;
        ldsDec[tid] = (float)(0.55 + 0.4 / (1.0 + exp(-(double)rdec[c])));
        ldsFrq[tid] = (float)(0.10 + 0.9 / (1.0 + exp(-(double)rfrq[c])));
        ldsT1[tid]  = t1a[c];
    }

    // ---- t=0 inline; own spikes DIRECT to A-LDS; ballots -> L3; prologue ----
    float base2[2][2][4];
    float mem[2][2][4], res[2][2][4];
    unsigned int pooled_pk[4] = {0, 0, 0, 0};
    char* ring = smem + LDS_RING + w * 12288;
    unsigned long long myb = 0;
#pragma unroll
    for (int m = 0; m < 2; ++m)
#pragma unroll
        for (int nt = 0; nt < 2; ++nt) {
            int c = cbase + w * 32 + nt * 16 + llo;
            float bb = b_in[c];
            float brv = b_rec[c];
#pragma unroll
            for (int fr = 0; fr < 4; ++fr) {
                int row = m * 16 + lhi * 4 + fr;
                float b0 = __fadd_rn(bacc[m][nt][fr], bb);
                base2[m][nt][fr] = __fadd_rn(b0, brv);
                float m_ = __fadd_rn(0.f, b0);
                int s = (m_ > 1.0f) ? 1 : 0;
                res[m][nt][fr] = 0.f;
                mem[m][nt][fr] = __fadd_rn(m_, -(float)s);
                pooled_pk[m * 2 + nt] += (unsigned int)s << (8 * fr);
                unsigned long long b = __ballot(s);
                myb = (lane == (m * 8 + nt * 4 + fr)) ? b : myb;
                *(unsigned char*)(smem + ((row * 1024 + c) ^ ((row & 7) << 4))) =
                    (unsigned char)s;
            }
        }
    if (lane < 16)
        __hip_atomic_store((unsigned long long*)(sx + q * 4096 + h * 1024 + w * 128 + lane * 8),
                           myb, __ATOMIC_RELAXED, __HIP_MEMORY_SCOPE_AGENT);
    __builtin_amdgcn_sched_barrier(0);
    {   // prologue: kt_seq[0]=4h, kt_seq[1]=4h+1
#pragma unroll
        for (int kk = 0; kk < 2; ++kk)
#pragma unroll
            for (int nt = 0; nt < 2; ++nt) {
                const signed char* b =
                    WrQ + (((size_t)(((4 * h + kk) * 64 + cg0 + nt) * 3)) << 10) + lane16;
                char* sl = ring + kk * 6144 + nt * 3072;
                glds16(b,        (void*)sl);
                glds16(b + 1024, (void*)(sl + 1024));
                glds16(b + 2048, (void*)(sl + 2048));
            }
    }
    __builtin_amdgcn_sched_barrier(0);
    asm volatile("s_waitcnt vmcnt(12)" ::: "memory");   // bits (oldest) retired
    SBARL();
    if (tid == 0)
        __hip_atomic_store(&flags[q * 4 + h], 1u,
                           __ATOMIC_RELAXED, __HIP_MEMORY_SCOPE_AGENT);

    // ---- phase C: steps 1..31 ----
    for (int t = 1; t < 32; ++t) {
        i32x4 acc[2][2][3] = {};

        // i = 0..1: OWN kts
#pragma unroll
        for (int i = 0; i < 2; ++i) {
            const int kt = 4 * h + i;
            const int P = (i & 1) * 6144;
            i32x4 Af0 = *(const i32x4*)(smem + ((llo * 1024 + kt * 64 + lhi * 16) ^ ax));
            i32x4 Af1 = *(const i32x4*)(smem + (((16 + llo) * 1024 + kt * 64 + lhi * 16) ^ ax));
            const int nkt = (kt + 2) & 15;
            const signed char* b0 = WrQ + (((size_t)((nkt * 64 + cg0) * 3)) << 10) + lane16;
            const signed char* b1 = WrQ + (((size_t)((nkt * 64 + cg0 + 1) * 3)) << 10) + lane16;
            RING_NT(P, 0, b0)
            RING_NT(P, 1, b1)
        }

        // per-thread poll + hoisted bits load (T14 split; consumed after i=3)
        unsigned long long Bbits = 0;
        int hsrc_t = 0, inner_t = 0;
        if (tid < 384) {
            int hh = tid >> 7;
            hsrc_t = hh + (hh >= h ? 1 : 0);
            inner_t = tid & 127;
            while (__hip_atomic_load(&flags[(t - 1) * 256 + q * 4 + hsrc_t],
                                     __ATOMIC_ACQUIRE, __HIP_MEMORY_SCOPE_AGENT) == 0)
                __builtin_amdgcn_s_sleep(2);
            Bbits = __hip_atomic_load(
                (unsigned long long*)(sx + (((t - 1) & 1) * 262144) + q * 4096
                                      + hsrc_t * 1024 + inner_t * 8),
                __ATOMIC_RELAXED, __HIP_MEMORY_SCOPE_AGENT);
        }

        // i = 2..3: OWN kts (hide the bits load's L3 latency)
#pragma unroll
        for (int i = 2; i < 4; ++i) {
            const int kt = 4 * h + i;
            const int P = (i & 1) * 6144;
            i32x4 Af0 = *(const i32x4*)(smem + ((llo * 1024 + kt * 64 + lhi * 16) ^ ax));
            i32x4 Af1 = *(const i32x4*)(smem + (((16 + llo) * 1024 + kt * 64 + lhi * 16) ^ ax));
            const int nkt = (kt + 2) & 15;
            const signed char* b0 = WrQ + (((size_t)((nkt * 64 + cg0) * 3)) << 10) + lane16;
            const signed char* b1 = WrQ + (((size_t)((nkt * 64 + cg0 + 1) * 3)) << 10) + lane16;
            RING_NT(P, 0, b0)
            RING_NT(P, 1, b1)
        }

        // expand the 384 partner ballots
        if (tid < 384) {
            int l = inner_t & 15, wsrc = inner_t >> 4;
            int fr = l & 3, nt = (l >> 2) & 1, m = (l >> 3) & 1;
            int colb = hsrc_t * 256 + wsrc * 32 + nt * 16;
#pragma unroll
            for (int l2 = 0; l2 < 4; ++l2) {
                int row = m * 16 + l2 * 4 + fr;
                unsigned int b16 = (unsigned int)(Bbits >> (l2 * 16)) & 0xFFFFu;
                i32x4 v;
#pragma unroll
                for (int qq = 0; qq < 4; ++qq) {
                    unsigned int b4 = (b16 >> (qq * 4)) & 0xFu;
                    v[qq] = (int)((b4 & 1u) | ((b4 >> 1) & 1u) << 8 |
                                  ((b4 >> 2) & 1u) << 16 | ((b4 >> 3) & 1u) << 24);
                }
                *(i32x4*)(smem + ((row * 1024 + colb) ^ ((row & 7) << 4))) = v;
            }
        }
        SBARL();

        // i = 4..13 steady (partner kts), 14..15 epilogue
#pragma unroll 2
        for (int i = 4; i < 14; ++i) {
            const int kt = (4 * h + i) & 15;
            const int P = (i & 1) * 6144;
            i32x4 Af0 = *(const i32x4*)(smem + ((llo * 1024 + kt * 64 + lhi * 16) ^ ax));
            i32x4 Af1 = *(const i32x4*)(smem + (((16 + llo) * 1024 + kt * 64 + lhi * 16) ^ ax));
            const int nkt = (4 * h + i + 2) & 15;
            const signed char* b0 = WrQ + (((size_t)((nkt * 64 + cg0) * 3)) << 10) + lane16;
            const signed char* b1 = WrQ + (((size_t)((nkt * 64 + cg0 + 1) * 3)) << 10) + lane16;
            RING_NT(P, 0, b0)
            RING_NT(P, 1, b1)
        }
        {
            const int kt = (4 * h + 14) & 15;
            i32x4 Af0 = *(const i32x4*)(smem + ((llo * 1024 + kt * 64 + lhi * 16) ^ ax));
            i32x4 Af1 = *(const i32x4*)(smem + (((16 + llo) * 1024 + kt * 64 + lhi * 16) ^ ax));
            RING_NTL(0, 0, 9) RING_NTL(0, 1, 6)
        }
        {
            const int kt = (4 * h + 15) & 15;
            i32x4 Af0 = *(const i32x4*)(smem + ((llo * 1024 + kt * 64 + lhi * 16) ^ ax));
            i32x4 Af1 = *(const i32x4*)(smem + (((16 + llo) * 1024 + kt * 64 + lhi * 16) ^ ax));
            RING_NTL(6144, 0, 3) RING_NTL(6144, 1, 0)
        }

        // state update (exact np op order); own spikes DIRECT to A (t<31)
        myb = 0;
#pragma unroll
        for (int m = 0; m < 2; ++m)
#pragma unroll
            for (int nt = 0; nt < 2; ++nt) {
                int lc = w * 32 + nt * 16 + llo;
                int c = cbase + lc;
                float dcc = ldsDec[lc], fqc = ldsFrq[lc], t1c = ldsT1[lc];
#pragma unroll
                for (int fr = 0; fr < 4; ++fr) {
                    int row = m * 16 + lhi * 4 + fr;
                    float s3 = (float)acc[m][nt][2][fr];
                    float s2 = fmaf(s3, QINV, (float)acc[m][nt][1][fr]);
                    float rec = __fmul_rn(fmaf(s2, QINV, (float)acc[m][nt][0][fr]), t1c);
                    float drive = __fadd_rn(base2[m][nt][fr], rec);
                    float rnew = __fadd_rn(__fmul_rn(dcc, res[m][nt][fr]),
                                           __fmul_rn(fqc, mem[m][nt][fr]));
                    float tt = __fadd_rn(__fmul_rn(dcc, mem[m][nt][fr]), drive);
                    float m_ = __fadd_rn(tt, -rnew);
                    int s = (m_ > 1.0f) ? 1 : 0;
                    res[m][nt][fr] = rnew;
                    mem[m][nt][fr] = __fadd_rn(m_, -(float)s);
                    pooled_pk[m * 2 + nt] += (unsigned int)s << (8 * fr);
                    unsigned long long b = __ballot(s);
                    myb = (lane == (m * 8 + nt * 4 + fr)) ? b : myb;
                    if (t < 31)
                        *(unsigned char*)(smem + ((row * 1024 + c) ^ ((row & 7) << 4))) =
                            (unsigned char)s;
                }
            }
        if (t < 31) {
            if (lane < 16)
                __hip_atomic_store((unsigned long long*)(sx + ((t & 1) * 262144) + q * 4096
                                                         + h * 1024 + w * 128 + lane * 8),
                                   myb, __ATOMIC_RELAXED, __HIP_MEMORY_SCOPE_AGENT);
            __builtin_amdgcn_sched_barrier(0);
#pragma unroll
            for (int kk = 0; kk < 2; ++kk)
#pragma unroll
                for (int nt = 0; nt < 2; ++nt) {
                    const signed char* b =
                        WrQ + (((size_t)(((4 * h + kk) * 64 + cg0 + nt) * 3)) << 10) + lane16;
                    char* sl = ring + kk * 6144 + nt * 3072;
                    glds16(b,        (void*)sl);
                    glds16(b + 1024, (void*)(sl + 1024));
                    glds16(b + 2048, (void*)(sl + 2048));
                }
            __builtin_amdgcn_sched_barrier(0);
            asm volatile("s_waitcnt vmcnt(12)" ::: "memory");
            SBARL();
            if (tid == 0)
                __hip_atomic_store(&flags[t * 256 + q * 4 + h], 1u,
                                   __ATOMIC_RELAXED, __HIP_MEMORY_SCOPE_AGENT);
        }
    }

    // ---- phase D: own-cols f64 partial; h>0 ship; h==0 combine ----
    __syncthreads();
    float* plds = (float*)(smem + LDS_PLDS);
#pragma unroll
    for (int m = 0; m < 2; ++m)
#pragma unroll
        for (int nt = 0; nt < 2; ++nt) {
            int lc = w * 32 + nt * 16 + llo;
#pragma unroll
            for (int fr = 0; fr < 4; ++fr)
                plds[(m * 16 + lhi * 4 + fr) * 264 + lc] =
                    (float)((pooled_pk[m * 2 + nt] >> (8 * fr)) & 255u) * 0.03125f;
        }
    __syncthreads();
    double part = 0.0;
    {
        int row = tid >> 4, o = tid & 15;
        for (int j = 0; j < 256; ++j)
            part += (double)plds[row * 264 + j] * (double)W_out[(size_t)(cbase + j) * 16 + o];
    }
    if (h != 0) {
        __hip_atomic_store(&pdb[(q * 4 + h) * 512 + tid], __double_as_longlong(part),
                           __ATOMIC_RELAXED, __HIP_MEMORY_SCOPE_AGENT);
        __syncthreads();
        if (tid == 0)
            __hip_atomic_store(&flags[32 * 256 + q * 4 + h], 1u,
                               __ATOMIC_RELEASE, __HIP_MEMORY_SCOPE_AGENT);
    } else {
        if (tid == 0) {
#pragma unroll
            for (int hp = 1; hp < 4; ++hp)
                while (__hip_atomic_load(&flags[32 * 256 + q * 4 + hp],
                                         __ATOMIC_ACQUIRE, __HIP_MEMORY_SCOPE_AGENT) == 0)
                    __builtin_amdgcn_s_sleep(2);
        }
        __syncthreads();
        {
            int row = tid >> 4, o = tid & 15;
            double tot = part;
#pragma unroll
            for (int hp = 1; hp < 4; ++hp) {
                unsigned long long pb = __hip_atomic_load(&pdb[(q * 4 + hp) * 512 + tid],
                                                          __ATOMIC_RELAXED,
                                                          __HIP_MEMORY_SCOPE_AGENT);
                tot += __longlong_as_double(pb);
            }
            out[(size_t)(r0 + row) * 16 + o] = __fadd_rn((float)tot, b_out[o]);
        }
    }
}

extern "C" void kernel_launch(void* const* d_in, const int* in_sizes, int n_in,
                              void* d_out, int out_size, void* d_ws, size_t ws_size,
                              hipStream_t stream) {
    const float* fused = (const float*)d_in[0];
    const float* W_in  = (const float*)d_in[1];
    const float* b_in  = (const float*)d_in[2];
    const float* W_rec = (const float*)d_in[3];
    const float* b_rec = (const float*)d_in[4];
    const float* W_out = (const float*)d_in[5];
    const float* b_out = (const float*)d_in[6];
    const float* rdec  = (const float*)d_in[7];
    const float* rfrq  = (const float*)d_in[8];

    char* ws = (char*)d_ws;
    signed char*        WrQ   = (signed char*)(ws);
    float*              t1a   = (float*)(ws + 3145728);
    unsigned int*       t1u   = (unsigned int*)(ws + 3149824);
    unsigned short*     Wi1   = (unsigned short*)(ws + 3407872);
    unsigned short*     Wi2   = (unsigned short*)(ws + 4980736);
    unsigned short*     Wi3   = (unsigned short*)(ws + 6553600);
    char*               sx    = ws + 8126464;
    unsigned long long* pdb   = (unsigned long long*)(ws + 8650752);
    unsigned int*       flags = (unsigned int*)(ws + 9699328);
    float* out = (float*)d_out;

    hipFuncSetAttribute((const void*)k_main,
                        hipFuncAttributeMaxDynamicSharedMemorySize, LDS_TOTAL);

    hipMemsetAsync(flags, 0, 33 * 256 * 4, stream);
    hipMemsetAsync(t1u, 0, 4096, stream);
    hipLaunchKernelGGL(k_colmax, dim3(128), dim3(256), 0, stream, W_rec, t1u);
    hipLaunchKernelGGL(k_packq, dim3(4096), dim3(256), 0, stream, W_rec, t1u, t1a, WrQ);
    hipLaunchKernelGGL(k_pack3, dim3(3072), dim3(256), 0, stream, W_in, Wi1, Wi2, Wi3, 768);

    void* args[] = {(void*)&fused, (void*)&Wi1, (void*)&Wi2, (void*)&Wi3, (void*)&b_in,
                    (void*)&WrQ, (void*)&t1a, (void*)&b_rec, (void*)&rdec, (void*)&rfrq,
                    (void*)&W_out, (void*)&b_out, (void*)&sx, (void*)&pdb, (void*)&flags,
                    (void*)&out};
    hipLaunchCooperativeKernel((void*)k_main, dim3(256), dim3(512), args, LDS_TOTAL, stream);
}

// Round 20
// 449.201 us; speedup vs baseline: 2.0306x; 1.6779x over previous
//
#include <hip/hip_runtime.h>

typedef __attribute__((ext_vector_type(4))) float f32x4;
typedef __attribute__((ext_vector_type(4))) int   i32x4;
typedef __attribute__((ext_vector_type(8))) short s16x8;

#define MFMA16(a, b, c)  __builtin_amdgcn_mfma_f32_16x16x32_bf16((a), (b), (c), 0, 0, 0)
#define MFMAI8(a, b, c)  __builtin_amdgcn_mfma_i32_16x16x64_i8((a), (b), (c), 0, 0, 0)

#define QINV (1.0f / 252.0f)

typedef __attribute__((address_space(3))) unsigned int lds_uint;
typedef const __attribute__((address_space(1))) unsigned int glob_uint;
__device__ __forceinline__ void glds16(const void* g, void* l) {
    __builtin_amdgcn_global_load_lds((glob_uint*)g, (lds_uint*)l, 16, 0, 0);
}

#define SBARL()                                                                \
    {                                                                          \
        __builtin_amdgcn_sched_barrier(0);                                     \
        asm volatile("s_waitcnt lgkmcnt(0)" ::: "memory");                     \
        __builtin_amdgcn_s_barrier();                                          \
        __builtin_amdgcn_sched_barrier(0);                                     \
    }
#define SBAR()                                                                 \
    {                                                                          \
        __builtin_amdgcn_sched_barrier(0);                                     \
        __builtin_amdgcn_s_barrier();                                          \
        __builtin_amdgcn_sched_barrier(0);                                     \
    }

// ---------- bf16 helpers (RNE) ----------
__device__ inline unsigned short f2bf(float f) {
    unsigned int u = __float_as_uint(f);
    return (unsigned short)((u + 0x7FFFu + ((u >> 16) & 1u)) >> 16);
}
__device__ inline float bf2f(unsigned short b) {
    return __uint_as_float(((unsigned int)b) << 16);
}

// ---------- pack W [K][1024] f32 -> THREE bf16 levels (W_in path) ----------
__global__ __launch_bounds__(256) void k_pack3(const float* __restrict__ W,
                                               unsigned short* __restrict__ L1,
                                               unsigned short* __restrict__ L2,
                                               unsigned short* __restrict__ L3,
                                               int K) {
    int idx = blockIdx.x * 256 + threadIdx.x;
    if (idx >= K * 1024) return;
    int k = idx >> 10;
    int n = idx & 1023;
    float x = W[idx];
    unsigned short h1 = f2bf(x);  float r1 = x - bf2f(h1);
    unsigned short h2 = f2bf(r1); float r2 = r1 - bf2f(h2);
    unsigned short h3 = f2bf(r2);
    size_t o = ((size_t)(k >> 5) << 15) + ((size_t)n << 5) + (k & 31);
    L1[o] = h1; L2[o] = h2; L3[o] = h3;
}

// ---------- per-column max|W_rec| (COALESCED; bit-monotone atomicMax) ----------
__global__ __launch_bounds__(256) void k_colmax(const float* __restrict__ W,
                                                unsigned int* __restrict__ t1u) {
    __shared__ float cmax[1024];
    for (int i = threadIdx.x; i < 1024; i += 256) cmax[i] = 0.f;
    __syncthreads();
    int k0 = blockIdx.x * 8;
    for (int r = 0; r < 8; ++r)
        for (int c = threadIdx.x; c < 1024; c += 256)
            cmax[c] = fmaxf(cmax[c], fabsf(W[(size_t)(k0 + r) * 1024 + c]));
    __syncthreads();
    for (int c = threadIdx.x; c < 1024; c += 256)
        atomicMax(&t1u[c], __float_as_uint(cmax[c]));
}

// ---------- pack W_rec -> 3 i8 digits as MFMA-ready 1KB frags; emit t1a ----------
__global__ __launch_bounds__(256) void k_packq(const float* __restrict__ W,
                                               const unsigned int* __restrict__ t1u,
                                               float* __restrict__ t1a,
                                               signed char* __restrict__ Q) {
    int idx = blockIdx.x * 256 + threadIdx.x;   // k*1024 + n
    int k = idx >> 10;
    int n = idx & 1023;
    float x = W[idx];
    float T1 = fmaxf(__uint_as_float(t1u[n]), 1e-30f) * (1.0f / 126.0f);
    if (k == 0) t1a[n] = T1;
    float T2 = T1 * QINV;
    float T3 = T2 * QINV;
    float q1 = rintf(x / T1);  float r1 = fmaf(-q1, T1, x);
    float q2 = rintf(r1 / T2); float r2 = fmaf(-q2, T2, r1);
    float q3 = rintf(r2 / T3);
    int kt = k >> 6, cg = n >> 4;
    int lane = (((k >> 4) & 3) << 4) | (n & 15);
    size_t base = ((size_t)((kt * 64 + cg) * 3)) << 10;
    size_t lj = (size_t)lane * 16 + (k & 15);
    Q[base + lj]        = (signed char)(int)q1;
    Q[base + 1024 + lj] = (signed char)(int)q2;
    Q[base + 2048 + lj] = (signed char)(int)q3;
}

// ---------- main: EXACT R17 structure (445us verified). Cooperative 256
// blocks x 512 thr; quad rows 32q..+32, member h cols h*256..+256. Cyclic kt
// order (own kts first) hides the pairwise L3 exchange; poll by wave-0 only;
// expansion (with its one-time ring drain) strictly between SBAR/SBARL. ----
#define FSTR 770
#define LDS_SPK    0
#define LDS_DEC    32768
#define LDS_FRQ    33792
#define LDS_T1     34816
#define LDS_RING   35840
#define LDS_FUSED  35840
#define LDS_PLDS   35840
#define LDS_TOTAL  134400

#define RING_NT(P, nt, BSRC)                                                   \
    {                                                                          \
        asm volatile("s_waitcnt vmcnt(9)" ::: "memory");                       \
        __builtin_amdgcn_sched_barrier(0);                                     \
        const char* sl = ring + (P) + (nt) * 3072;                             \
        i32x4 Bv0 = *(const i32x4*)(sl + lane16);                              \
        i32x4 Bv1 = *(const i32x4*)(sl + 1024 + lane16);                       \
        i32x4 Bv2 = *(const i32x4*)(sl + 2048 + lane16);                       \
        acc[0][nt][0] = MFMAI8(Af0, Bv0, acc[0][nt][0]);                       \
        acc[1][nt][0] = MFMAI8(Af1, Bv0, acc[1][nt][0]);                       \
        acc[0][nt][1] = MFMAI8(Af0, Bv1, acc[0][nt][1]);                       \
        acc[1][nt][1] = MFMAI8(Af1, Bv1, acc[1][nt][1]);                       \
        acc[0][nt][2] = MFMAI8(Af0, Bv2, acc[0][nt][2]);                       \
        acc[1][nt][2] = MFMAI8(Af1, Bv2, acc[1][nt][2]);                       \
        __builtin_amdgcn_sched_barrier(0);                                     \
        glds16((BSRC),        (void*)sl);                                      \
        glds16((BSRC) + 1024, (void*)(sl + 1024));                             \
        glds16((BSRC) + 2048, (void*)(sl + 2048));                             \
    }
#define RING_NTL(P, nt, N)                                                     \
    {                                                                          \
        asm volatile("s_waitcnt vmcnt(" #N ")" ::: "memory");                  \
        __builtin_amdgcn_sched_barrier(0);                                     \
        const char* sl = ring + (P) + (nt) * 3072;                             \
        i32x4 Bv0 = *(const i32x4*)(sl + lane16);                              \
        i32x4 Bv1 = *(const i32x4*)(sl + 1024 + lane16);                       \
        i32x4 Bv2 = *(const i32x4*)(sl + 2048 + lane16);                       \
        acc[0][nt][0] = MFMAI8(Af0, Bv0, acc[0][nt][0]);                       \
        acc[1][nt][0] = MFMAI8(Af1, Bv0, acc[1][nt][0]);                       \
        acc[0][nt][1] = MFMAI8(Af0, Bv1, acc[0][nt][1]);                       \
        acc[1][nt][1] = MFMAI8(Af1, Bv1, acc[1][nt][1]);                       \
        acc[0][nt][2] = MFMAI8(Af0, Bv2, acc[0][nt][2]);                       \
        acc[1][nt][2] = MFMAI8(Af1, Bv2, acc[1][nt][2]);                       \
    }

__global__ __launch_bounds__(512, 2) void k_main(const float* __restrict__ fused,
                                                 const unsigned short* __restrict__ Wi1,
                                                 const unsigned short* __restrict__ Wi2,
                                                 const unsigned short* __restrict__ Wi3,
                                                 const float* __restrict__ b_in,
                                                 const signed char* __restrict__ WrQ,
                                                 const float* __restrict__ t1a,
                                                 const float* __restrict__ b_rec,
                                                 const float* __restrict__ rdec,
                                                 const float* __restrict__ rfrq,
                                                 const float* __restrict__ W_out,
                                                 const float* __restrict__ b_out,
                                                 char* __restrict__ sx,
                                                 unsigned long long* __restrict__ pdb,
                                                 unsigned int* __restrict__ flags,
                                                 float* __restrict__ out) {
    extern __shared__ __align__(16) char smem[];
    const int tid = threadIdx.x;
    const int w = tid >> 6, lane = tid & 63;
    const int llo = lane & 15, lhi = lane >> 4;
    const int bid = blockIdx.x;
    const int q = bid >> 2, h = bid & 3;
    const int r0 = q * 32;
    const int cbase = h * 256;
    const int cg0 = h * 16 + w * 2;
    const int lane16 = lane * 16;
    const int ax = (llo & 7) << 4;

    // ---- phase A ----
    float* fl = (float*)(smem + LDS_FUSED);
    for (int i = tid; i < 32 * 768; i += 512) {
        int rr = i / 768, cc = i - rr * 768;
        fl[rr * FSTR + cc] = fused[(size_t)(r0 + rr) * 768 + cc];
    }
    __syncthreads();

    // ---- phase B ----
    f32x4 bacc[2][2] = {};
    for (int kt = 0; kt < 24; ++kt) {
        s16x8 a1v[2], a2v[2], a3v[2];
#pragma unroll
        for (int m = 0; m < 2; ++m) {
            const float* ap = fl + (m * 16 + llo) * FSTR + kt * 32 + lhi * 8;
#pragma unroll
            for (int j = 0; j < 8; ++j) {
                float x = ap[j];
                unsigned short h1 = f2bf(x);  float r1 = x - bf2f(h1);
                unsigned short h2 = f2bf(r1); float r2 = r1 - bf2f(h2);
                a1v[m][j] = (short)h1; a2v[m][j] = (short)h2; a3v[m][j] = (short)f2bf(r2);
            }
        }
#pragma unroll
        for (int nt = 0; nt < 2; ++nt) {
            int c = cbase + w * 32 + nt * 16 + llo;
            size_t boff = ((size_t)(kt * 1024 + c) << 5) + lhi * 8;
            s16x8 b1 = *(const s16x8*)&Wi1[boff];
            s16x8 b2 = *(const s16x8*)&Wi2[boff];
            s16x8 b3 = *(const s16x8*)&Wi3[boff];
#pragma unroll
            for (int m = 0; m < 2; ++m) {
                bacc[m][nt] = MFMA16(a1v[m], b1, bacc[m][nt]);
                bacc[m][nt] = MFMA16(a1v[m], b2, bacc[m][nt]);
                bacc[m][nt] = MFMA16(a2v[m], b1, bacc[m][nt]);
                bacc[m][nt] = MFMA16(a2v[m], b2, bacc[m][nt]);
                bacc[m][nt] = MFMA16(a1v[m], b3, bacc[m][nt]);
                bacc[m][nt] = MFMA16(a3v[m], b1, bacc[m][nt]);
            }
        }
    }
    __syncthreads();

    // ---- params ----
    float* ldsDec = (float*)(smem + LDS_DEC);
    float* ldsFrq = (float*)(smem + LDS_FRQ);
    float* ldsT1  = (float*)(smem + LDS_T1);
    if (tid < 256) {
        int c = cbase + tid;
        ldsDec[tid] = (float)(0.55 + 0.4 / (1.0 + exp(-(double)rdec[c])));
        ldsFrq[tid] = (float)(0.10 + 0.9 / (1.0 + exp(-(double)rfrq[c])));
        ldsT1[tid]  = t1a[c];
    }

    // ---- t=0 inline; own spikes DIRECT to A-LDS; ballots -> L3; prologue ----
    float base2[2][2][4];
    float mem[2][2][4], res[2][2][4];
    unsigned int pooled_pk[4] = {0, 0, 0, 0};
    char* ring = smem + LDS_RING + w * 12288;
    unsigned long long myb = 0;
#pragma unroll
    for (int m = 0; m < 2; ++m)
#pragma unroll
        for (int nt = 0; nt < 2; ++nt) {
            int c = cbase + w * 32 + nt * 16 + llo;
            float bb = b_in[c];
            float brv = b_rec[c];
#pragma unroll
            for (int fr = 0; fr < 4; ++fr) {
                int row = m * 16 + lhi * 4 + fr;
                float b0 = __fadd_rn(bacc[m][nt][fr], bb);
                base2[m][nt][fr] = __fadd_rn(b0, brv);
                float m_ = __fadd_rn(0.f, b0);
                int s = (m_ > 1.0f) ? 1 : 0;
                res[m][nt][fr] = 0.f;
                mem[m][nt][fr] = __fadd_rn(m_, -(float)s);
                pooled_pk[m * 2 + nt] += (unsigned int)s << (8 * fr);
                unsigned long long b = __ballot(s);
                myb = (lane == (m * 8 + nt * 4 + fr)) ? b : myb;
                *(unsigned char*)(smem + ((row * 1024 + c) ^ ((row & 7) << 4))) =
                    (unsigned char)s;
            }
        }
    if (lane < 16)
        __hip_atomic_store((unsigned long long*)(sx + q * 4096 + h * 1024 + w * 128 + lane * 8),
                           myb, __ATOMIC_RELAXED, __HIP_MEMORY_SCOPE_AGENT);
    __builtin_amdgcn_sched_barrier(0);
    {
#pragma unroll
        for (int kk = 0; kk < 2; ++kk)
#pragma unroll
            for (int nt = 0; nt < 2; ++nt) {
                const signed char* b =
                    WrQ + (((size_t)(((4 * h + kk) * 64 + cg0 + nt) * 3)) << 10) + lane16;
                char* sl = ring + kk * 6144 + nt * 3072;
                glds16(b,        (void*)sl);
                glds16(b + 1024, (void*)(sl + 1024));
                glds16(b + 2048, (void*)(sl + 2048));
            }
    }
    __builtin_amdgcn_sched_barrier(0);
    asm volatile("s_waitcnt vmcnt(12)" ::: "memory");
    SBARL();
    if (tid == 0)
        __hip_atomic_store(&flags[q * 4 + h], 1u,
                           __ATOMIC_RELAXED, __HIP_MEMORY_SCOPE_AGENT);

    // ---- phase C: steps 1..31 ----
    for (int t = 1; t < 32; ++t) {
        i32x4 acc[2][2][3] = {};

        // i = 0..3: OWN kts
#pragma unroll
        for (int i = 0; i < 4; ++i) {
            const int kt = 4 * h + i;
            const int P = (i & 1) * 6144;
            i32x4 Af0 = *(const i32x4*)(smem + ((llo * 1024 + kt * 64 + lhi * 16) ^ ax));
            i32x4 Af1 = *(const i32x4*)(smem + (((16 + llo) * 1024 + kt * 64 + lhi * 16) ^ ax));
            const int nkt = (kt + 2) & 15;
            const signed char* b0 = WrQ + (((size_t)((nkt * 64 + cg0) * 3)) << 10) + lane16;
            const signed char* b1 = WrQ + (((size_t)((nkt * 64 + cg0 + 1) * 3)) << 10) + lane16;
            RING_NT(P, 0, b0)
            RING_NT(P, 1, b1)
        }

        // poll partner flags (wave 0 only; other waves' rings stay in flight)
        if (tid < 4 && tid != h) {
            while (__hip_atomic_load(&flags[(t - 1) * 256 + q * 4 + tid],
                                     __ATOMIC_ACQUIRE, __HIP_MEMORY_SCOPE_AGENT) == 0)
                __builtin_amdgcn_s_sleep(2);
        }
        SBAR();
        // expand the 384 partner ballots (one-time ring drain for these waves)
        if (tid < 384) {
            int hh = tid >> 7;
            int hsrc = hh + (hh >= h ? 1 : 0);
            int inner = tid & 127;
            unsigned long long B = __hip_atomic_load(
                (unsigned long long*)(sx + (((t - 1) & 1) * 262144) + q * 4096
                                      + hsrc * 1024 + inner * 8),
                __ATOMIC_RELAXED, __HIP_MEMORY_SCOPE_AGENT);
            int l = inner & 15, wsrc = inner >> 4;
            int fr = l & 3, nt = (l >> 2) & 1, m = (l >> 3) & 1;
            int colb = hsrc * 256 + wsrc * 32 + nt * 16;
#pragma unroll
            for (int l2 = 0; l2 < 4; ++l2) {
                int row = m * 16 + l2 * 4 + fr;
                unsigned int b16 = (unsigned int)(B >> (l2 * 16)) & 0xFFFFu;
                i32x4 v;
#pragma unroll
                for (int qq = 0; qq < 4; ++qq) {
                    unsigned int b4 = (b16 >> (qq * 4)) & 0xFu;
                    v[qq] = (int)((b4 & 1u) | ((b4 >> 1) & 1u) << 8 |
                                  ((b4 >> 2) & 1u) << 16 | ((b4 >> 3) & 1u) << 24);
                }
                *(i32x4*)(smem + ((row * 1024 + colb) ^ ((row & 7) << 4))) = v;
            }
        }
        SBARL();

        // i = 4..13 steady (partner kts), 14..15 epilogue
#pragma unroll 2
        for (int i = 4; i < 14; ++i) {
            const int kt = (4 * h + i) & 15;
            const int P = (i & 1) * 6144;
            i32x4 Af0 = *(const i32x4*)(smem + ((llo * 1024 + kt * 64 + lhi * 16) ^ ax));
            i32x4 Af1 = *(const i32x4*)(smem + (((16 + llo) * 1024 + kt * 64 + lhi * 16) ^ ax));
            const int nkt = (4 * h + i + 2) & 15;
            const signed char* b0 = WrQ + (((size_t)((nkt * 64 + cg0) * 3)) << 10) + lane16;
            const signed char* b1 = WrQ + (((size_t)((nkt * 64 + cg0 + 1) * 3)) << 10) + lane16;
            RING_NT(P, 0, b0)
            RING_NT(P, 1, b1)
        }
        {
            const int kt = (4 * h + 14) & 15;
            i32x4 Af0 = *(const i32x4*)(smem + ((llo * 1024 + kt * 64 + lhi * 16) ^ ax));
            i32x4 Af1 = *(const i32x4*)(smem + (((16 + llo) * 1024 + kt * 64 + lhi * 16) ^ ax));
            RING_NTL(0, 0, 9) RING_NTL(0, 1, 6)
        }
        {
            const int kt = (4 * h + 15) & 15;
            i32x4 Af0 = *(const i32x4*)(smem + ((llo * 1024 + kt * 64 + lhi * 16) ^ ax));
            i32x4 Af1 = *(const i32x4*)(smem + (((16 + llo) * 1024 + kt * 64 + lhi * 16) ^ ax));
            RING_NTL(6144, 0, 3) RING_NTL(6144, 1, 0)
        }

        // state update (exact np op order); own spikes DIRECT to A (t<31)
        myb = 0;
#pragma unroll
        for (int m = 0; m < 2; ++m)
#pragma unroll
            for (int nt = 0; nt < 2; ++nt) {
                int lc = w * 32 + nt * 16 + llo;
                int c = cbase + lc;
                float dcc = ldsDec[lc], fqc = ldsFrq[lc], t1c = ldsT1[lc];
#pragma unroll
                for (int fr = 0; fr < 4; ++fr) {
                    int row = m * 16 + lhi * 4 + fr;
                    float s3 = (float)acc[m][nt][2][fr];
                    float s2 = fmaf(s3, QINV, (float)acc[m][nt][1][fr]);
                    float rec = __fmul_rn(fmaf(s2, QINV, (float)acc[m][nt][0][fr]), t1c);
                    float drive = __fadd_rn(base2[m][nt][fr], rec);
                    float rnew = __fadd_rn(__fmul_rn(dcc, res[m][nt][fr]),
                                           __fmul_rn(fqc, mem[m][nt][fr]));
                    float tt = __fadd_rn(__fmul_rn(dcc, mem[m][nt][fr]), drive);
                    float m_ = __fadd_rn(tt, -rnew);
                    int s = (m_ > 1.0f) ? 1 : 0;
                    res[m][nt][fr] = rnew;
                    mem[m][nt][fr] = __fadd_rn(m_, -(float)s);
                    pooled_pk[m * 2 + nt] += (unsigned int)s << (8 * fr);
                    unsigned long long b = __ballot(s);
                    myb = (lane == (m * 8 + nt * 4 + fr)) ? b : myb;
                    if (t < 31)
                        *(unsigned char*)(smem + ((row * 1024 + c) ^ ((row & 7) << 4))) =
                            (unsigned char)s;
                }
            }
        if (t < 31) {
            if (lane < 16)
                __hip_atomic_store((unsigned long long*)(sx + ((t & 1) * 262144) + q * 4096
                                                         + h * 1024 + w * 128 + lane * 8),
                                   myb, __ATOMIC_RELAXED, __HIP_MEMORY_SCOPE_AGENT);
            __builtin_amdgcn_sched_barrier(0);
#pragma unroll
            for (int kk = 0; kk < 2; ++kk)
#pragma unroll
                for (int nt = 0; nt < 2; ++nt) {
                    const signed char* b =
                        WrQ + (((size_t)(((4 * h + kk) * 64 + cg0 + nt) * 3)) << 10) + lane16;
                    char* sl = ring + kk * 6144 + nt * 3072;
                    glds16(b,        (void*)sl);
                    glds16(b + 1024, (void*)(sl + 1024));
                    glds16(b + 2048, (void*)(sl + 2048));
                }
            __builtin_amdgcn_sched_barrier(0);
            asm volatile("s_waitcnt vmcnt(12)" ::: "memory");
            SBARL();
            if (tid == 0)
                __hip_atomic_store(&flags[t * 256 + q * 4 + h], 1u,
                                   __ATOMIC_RELAXED, __HIP_MEMORY_SCOPE_AGENT);
        }
    }

    // ---- phase D ----
    __syncthreads();
    float* plds = (float*)(smem + LDS_PLDS);
#pragma unroll
    for (int m = 0; m < 2; ++m)
#pragma unroll
        for (int nt = 0; nt < 2; ++nt) {
            int lc = w * 32 + nt * 16 + llo;
#pragma unroll
            for (int fr = 0; fr < 4; ++fr)
                plds[(m * 16 + lhi * 4 + fr) * 264 + lc] =
                    (float)((pooled_pk[m * 2 + nt] >> (8 * fr)) & 255u) * 0.03125f;
        }
    __syncthreads();
    double part = 0.0;
    {
        int row = tid >> 4, o = tid & 15;
        for (int j = 0; j < 256; ++j)
            part += (double)plds[row * 264 + j] * (double)W_out[(size_t)(cbase + j) * 16 + o];
    }
    if (h != 0) {
        __hip_atomic_store(&pdb[(q * 4 + h) * 512 + tid], __double_as_longlong(part),
                           __ATOMIC_RELAXED, __HIP_MEMORY_SCOPE_AGENT);
        __syncthreads();
        if (tid == 0)
            __hip_atomic_store(&flags[32 * 256 + q * 4 + h], 1u,
                               __ATOMIC_RELEASE, __HIP_MEMORY_SCOPE_AGENT);
    } else {
        if (tid == 0) {
#pragma unroll
            for (int hp = 1; hp < 4; ++hp)
                while (__hip_atomic_load(&flags[32 * 256 + q * 4 + hp],
                                         __ATOMIC_ACQUIRE, __HIP_MEMORY_SCOPE_AGENT) == 0)
                    __builtin_amdgcn_s_sleep(2);
        }
        __syncthreads();
        {
            int row = tid >> 4, o = tid & 15;
            double tot = part;
#pragma unroll
            for (int hp = 1; hp < 4; ++hp) {
                unsigned long long pb = __hip_atomic_load(&pdb[(q * 4 + hp) * 512 + tid],
                                                          __ATOMIC_RELAXED,
                                                          __HIP_MEMORY_SCOPE_AGENT);
                tot += __longlong_as_double(pb);
            }
            out[(size_t)(r0 + row) * 16 + o] = __fadd_rn((float)tot, b_out[o]);
        }
    }
}

extern "C" void kernel_launch(void* const* d_in, const int* in_sizes, int n_in,
                              void* d_out, int out_size, void* d_ws, size_t ws_size,
                              hipStream_t stream) {
    const float* fused = (const float*)d_in[0];
    const float* W_in  = (const float*)d_in[1];
    const float* b_in  = (const float*)d_in[2];
    const float* W_rec = (const float*)d_in[3];
    const float* b_rec = (const float*)d_in[4];
    const float* W_out = (const float*)d_in[5];
    const float* b_out = (const float*)d_in[6];
    const float* rdec  = (const float*)d_in[7];
    const float* rfrq  = (const float*)d_in[8];

    char* ws = (char*)d_ws;
    signed char*        WrQ   = (signed char*)(ws);
    float*              t1a   = (float*)(ws + 3145728);
    unsigned int*       t1u   = (unsigned int*)(ws + 3149824);
    unsigned short*     Wi1   = (unsigned short*)(ws + 3407872);
    unsigned short*     Wi2   = (unsigned short*)(ws + 4980736);
    unsigned short*     Wi3   = (unsigned short*)(ws + 6553600);
    char*               sx    = ws + 8126464;
    unsigned long long* pdb   = (unsigned long long*)(ws + 8650752);
    unsigned int*       flags = (unsigned int*)(ws + 9699328);
    float* out = (float*)d_out;

    hipFuncSetAttribute((const void*)k_main,
                        hipFuncAttributeMaxDynamicSharedMemorySize, LDS_TOTAL);

    hipMemsetAsync(flags, 0, 33 * 256 * 4, stream);
    hipMemsetAsync(t1u, 0, 4096, stream);
    hipLaunchKernelGGL(k_colmax, dim3(128), dim3(256), 0, stream, W_rec, t1u);
    hipLaunchKernelGGL(k_packq, dim3(4096), dim3(256), 0, stream, W_rec, t1u, t1a, WrQ);
    hipLaunchKernelGGL(k_pack3, dim3(3072), dim3(256), 0, stream, W_in, Wi1, Wi2, Wi3, 768);

    void* args[] = {(void*)&fused, (void*)&Wi1, (void*)&Wi2, (void*)&Wi3, (void*)&b_in,
                    (void*)&WrQ, (void*)&t1a, (void*)&b_rec, (void*)&rdec, (void*)&rfrq,
                    (void*)&W_out, (void*)&b_out, (void*)&sx, (void*)&pdb, (void*)&flags,
                    (void*)&out};
    hipLaunchCooperativeKernel((void*)k_main, dim3(256), dim3(512), args, LDS_TOTAL, stream);
}